// Round 4
// baseline (1195.716 us; speedup 1.0000x reference)
//
#include <hip/hip_runtime.h>
#include <math.h>

// Problem constants
#define D_FEAT 8192
#define T_RES  2048
#define NC4    2048          // float4 columns
#define LORD   16

// Persistent kernel geometry: 256 blocks x 512 threads, 1 block/CU, 8 rows/block.
#define NTHR   512
#define NBLK   256
#define ROWS   8
#define CPT    4             // float4 per thread (512*4 = 2048 float4 = 8192 floats)

// Workspace layout (float offsets). ~9.1 MB of the 268 MB ws.
#define OFF_Q    0                          // 16 x 8192 Lanczos basis
#define OFF_W    (LORD*D_FEAT)              // unscaled w vector
#define OFF_U    (OFF_W + D_FEAT)           // U[k][t] = (R q_k)_t, 16x2048
#define OFF_PART (OFF_U + LORD*T_RES)       // 256 x 8192 partial y
#define OFF_SCAL (OFF_PART + NBLK*D_FEAT)

#define SC_FF    0
#define SC_FHF   1
#define SC_NF2   2
#define SC_ALPHA 3    // 16
#define SC_BETA2 19   // 16
#define SC_C     35   // 16 steps x 17 slots
#define SC_COEF  307  // 16
#define SC_BCNT  336  // barrier arrive counter (uint)
#define SC_BGEN  337  // barrier generation (uint)
#define SCAL_N   352

// Fast device-wide barrier (all 256 blocks co-resident via cooperative launch).
// tid0: agent fence (L2 WB+INV for cross-XCD visibility) + arrive + spin on gen.
__device__ __forceinline__ void gbar(unsigned* cnt, unsigned* gen) {
    __syncthreads();
    if (threadIdx.x == 0) {
        __threadfence();  // release: drain + writeback dirty L2 device-wide
        unsigned g = __hip_atomic_load(gen, __ATOMIC_RELAXED, __HIP_MEMORY_SCOPE_AGENT);
        unsigned a = __hip_atomic_fetch_add(cnt, 1u, __ATOMIC_ACQ_REL,
                                            __HIP_MEMORY_SCOPE_AGENT);
        if (a == NBLK - 1u) {
            __hip_atomic_store(cnt, 0u, __ATOMIC_RELAXED, __HIP_MEMORY_SCOPE_AGENT);
            __hip_atomic_store(gen, g + 1u, __ATOMIC_RELEASE, __HIP_MEMORY_SCOPE_AGENT);
        } else {
            while (__hip_atomic_load(gen, __ATOMIC_RELAXED,
                                     __HIP_MEMORY_SCOPE_AGENT) == g)
                __builtin_amdgcn_s_sleep(1);
        }
        __threadfence();  // acquire: invalidate L1/L2 before consuming remote data
    }
    __syncthreads();
}

// Column reduce: block owns 8 float4 cols (bid*8 .. +8). 64 row-groups x 8 cols.
// Returns reduced float4 for lanes tid<8 (col = tid).
__device__ __forceinline__ float4 col_reduce(const float* __restrict__ part,
                                             int bid, int tid, float4* lds4)
{
    const float4* p4 = (const float4*)part;
    const int col = tid & 7, rg = tid >> 3;
    const int c4  = (bid << 3) + col;
    float4 acc = make_float4(0.f, 0.f, 0.f, 0.f);
    #pragma unroll
    for (int i = 0; i < 4; ++i) {
        float4 t = p4[(size_t)(rg*4 + i)*NC4 + c4];
        acc.x += t.x; acc.y += t.y; acc.z += t.z; acc.w += t.w;
    }
    lds4[tid] = acc;
    __syncthreads();
    float4 a2 = make_float4(0.f, 0.f, 0.f, 0.f);
    if (tid < 64) {
        a2 = lds4[tid];
        #pragma unroll
        for (int i = 1; i < 8; ++i) {
            float4 t = lds4[tid + 64*i];
            a2.x += t.x; a2.y += t.y; a2.z += t.z; a2.w += t.w;
        }
        #pragma unroll
        for (int m = 8; m < 64; m <<= 1) {
            a2.x += __shfl_xor(a2.x, m, 64);
            a2.y += __shfl_xor(a2.y, m, 64);
            a2.z += __shfl_xor(a2.z, m, 64);
            a2.w += __shfl_xor(a2.w, m, 64);
        }
    }
    return a2;
}

__global__ __launch_bounds__(NTHR, 2) void k_all(
    const float* __restrict__ Rm, const float* __restrict__ f,
    const float* __restrict__ Dm, float* __restrict__ out,
    float* __restrict__ ws)
{
    __shared__ float4 lds4[NTHR];
    __shared__ float  ldsr[64];
    __shared__ float  cs[LORD];

    float* Qb   = ws + OFF_Q;
    float* W    = ws + OFF_W;
    float* U    = ws + OFF_U;
    float* part = ws + OFF_PART;
    float* scal = ws + OFF_SCAL;
    unsigned* bcnt = (unsigned*)(scal + SC_BCNT);
    unsigned* bgen = (unsigned*)(scal + SC_BGEN);

    const int tid  = threadIdx.x, bid = blockIdx.x;
    const int wave = tid >> 6,    lane = tid & 63;

    // Load this block's 8 R-rows into registers ONCE (held across all 17 steps).
    const float4* R4 = (const float4*)Rm;
    const size_t  t0 = (size_t)bid * ROWS;
    float4 row[ROWS][CPT];   // 128 regs (VGPR/AGPR unified file)
    #pragma unroll
    for (int r = 0; r < ROWS; ++r)
        #pragma unroll
        for (int c = 0; c < CPT; ++c)
            row[r][c] = R4[(t0 + r)*NC4 + tid + NTHR*c];

    // ===== INIT phase 1: u = R f ; partials of Hf = -R^T u ; f.f ; f.Hf =====
    {
        const float4* v4 = (const float4*)f;
        float4 q[CPT];
        #pragma unroll
        for (int c = 0; c < CPT; ++c) q[c] = v4[tid + NTHR*c];
        if (bid == 0) {
            float ffp = 0.f;
            #pragma unroll
            for (int c = 0; c < CPT; ++c)
                ffp += q[c].x*q[c].x + q[c].y*q[c].y + q[c].z*q[c].z + q[c].w*q[c].w;
            #pragma unroll
            for (int o = 32; o > 0; o >>= 1) ffp += __shfl_down(ffp, o, 64);
            if (lane == 0) atomicAdd(scal + SC_FF, ffp);
        }
        float s[ROWS];
        #pragma unroll
        for (int r = 0; r < ROWS; ++r) {
            float acc = 0.f;
            #pragma unroll
            for (int c = 0; c < CPT; ++c)
                acc += row[r][c].x*q[c].x + row[r][c].y*q[c].y
                     + row[r][c].z*q[c].z + row[r][c].w*q[c].w;
            s[r] = acc;
        }
        #pragma unroll
        for (int o = 32; o > 0; o >>= 1)
            #pragma unroll
            for (int r = 0; r < ROWS; ++r) s[r] += __shfl_down(s[r], o, 64);
        if (lane == 0) {
            #pragma unroll
            for (int r = 0; r < ROWS; ++r) ldsr[r*8 + wave] = s[r];
        }
        __syncthreads();
        float val = ldsr[lane];
        #pragma unroll
        for (int m = 1; m < 8; m <<= 1) val += __shfl_xor(val, m, 64);
        float u[ROWS];
        #pragma unroll
        for (int r = 0; r < ROWS; ++r) u[r] = __shfl(val, r*8, 64);
        float4* p4 = (float4*)part + (size_t)bid*NC4;
        #pragma unroll
        for (int c = 0; c < CPT; ++c) {
            float4 y = make_float4(0.f, 0.f, 0.f, 0.f);
            #pragma unroll
            for (int r = 0; r < ROWS; ++r) {
                y.x -= u[r]*row[r][c].x; y.y -= u[r]*row[r][c].y;
                y.z -= u[r]*row[r][c].z; y.w -= u[r]*row[r][c].w;
            }
            p4[tid + NTHR*c] = y;
        }
        if (tid == 0) {
            float ap = 0.f;
            #pragma unroll
            for (int r = 0; r < ROWS; ++r) ap += u[r]*u[r];
            atomicAdd(scal + SC_FHF, -ap);
        }
    }
    gbar(bcnt, bgen);

    // ===== INIT phase 2: F = E f - Hf ; W = F ; nf2 =====
    {
        float4 y = col_reduce(part, bid, tid, lds4);
        if (tid < 8) {
            const int c4 = (bid << 3) + tid;
            const float E = scal[SC_FHF] / (scal[SC_FF] + 1e-15f);
            const float4 fv = ((const float4*)f)[c4];
            float4 F = make_float4(E*fv.x - y.x, E*fv.y - y.y,
                                   E*fv.z - y.z, E*fv.w - y.w);
            float n2 = F.x*F.x + F.y*F.y + F.z*F.z + F.w*F.w;
            n2 += __shfl_down(n2, 4, 64);
            n2 += __shfl_down(n2, 2, 64);
            n2 += __shfl_down(n2, 1, 64);
            if (tid == 0) atomicAdd(scal + SC_NF2, n2);
            ((float4*)W)[c4] = F;
        }
    }
    gbar(bcnt, bgen);

    // ===== Lanczos: 16 steps =====
    for (int j = 0; j < LORD; ++j) {
        // phase 1: q = W/||W|| ; u = R q ; partial y = -u^T rows ; a, c_k atomics
        const float b2prev = (j == 0) ? scal[SC_NF2] : scal[SC_BETA2 + (j - 1)];
        const float scale  = rsqrtf(fmaxf(b2prev, 1e-60f));  // ref: w/max(b,1e-30)
        const float4* v4 = (const float4*)W;
        float4 q[CPT];
        #pragma unroll
        for (int c = 0; c < CPT; ++c) {
            float4 t = v4[tid + NTHR*c];
            t.x *= scale; t.y *= scale; t.z *= scale; t.w *= scale;
            q[c] = t;
        }
        if (bid == 0) {   // publish Q[j]
            float4* Q4 = (float4*)(Qb + (size_t)j*D_FEAT);
            #pragma unroll
            for (int c = 0; c < CPT; ++c) Q4[tid + NTHR*c] = q[c];
        }
        float s[ROWS];
        #pragma unroll
        for (int r = 0; r < ROWS; ++r) {
            float acc = 0.f;
            #pragma unroll
            for (int c = 0; c < CPT; ++c)
                acc += row[r][c].x*q[c].x + row[r][c].y*q[c].y
                     + row[r][c].z*q[c].z + row[r][c].w*q[c].w;
            s[r] = acc;
        }
        #pragma unroll
        for (int o = 32; o > 0; o >>= 1)
            #pragma unroll
            for (int r = 0; r < ROWS; ++r) s[r] += __shfl_down(s[r], o, 64);
        if (lane == 0) {
            #pragma unroll
            for (int r = 0; r < ROWS; ++r) ldsr[r*8 + wave] = s[r];
        }
        __syncthreads();
        float val = ldsr[lane];
        #pragma unroll
        for (int m = 1; m < 8; m <<= 1) val += __shfl_xor(val, m, 64);
        if (wave == 0 && (lane & 7) == 0)
            U[(size_t)j*T_RES + t0 + (lane >> 3)] = val;
        float u[ROWS];
        #pragma unroll
        for (int r = 0; r < ROWS; ++r) u[r] = __shfl(val, r*8, 64);
        float4* p4 = (float4*)part + (size_t)bid*NC4;
        #pragma unroll
        for (int c = 0; c < CPT; ++c) {
            float4 y = make_float4(0.f, 0.f, 0.f, 0.f);
            #pragma unroll
            for (int r = 0; r < ROWS; ++r) {
                y.x -= u[r]*row[r][c].x; y.y -= u[r]*row[r][c].y;
                y.z -= u[r]*row[r][c].z; y.w -= u[r]*row[r][c].w;
            }
            p4[tid + NTHR*c] = y;
        }
        if (tid == 0) {
            float ap = 0.f;
            #pragma unroll
            for (int r = 0; r < ROWS; ++r) ap += u[r]*u[r];
            atomicAdd(scal + SC_ALPHA + j, -ap);
            atomicAdd(scal + SC_C + j*17 + j, -ap);   // c_raw_j = a_j
        }
        if (wave == 0 && lane < j) {   // c_raw_k = Q_k.y = -U_k.u
            float cp = 0.f;
            #pragma unroll
            for (int r = 0; r < ROWS; ++r)
                cp += U[(size_t)lane*T_RES + t0 + r] * u[r];
            atomicAdd(scal + SC_C + j*17 + lane, -cp);
        }
        gbar(bcnt, bgen);

        if (j == LORD - 1) break;   // beta[15]/w_16 unused by the reference

        // phase 2: w = colsum(part) - sum_{k<=j} c_k Q_k ; beta2[j] = |w|^2
        {
            float4 y = col_reduce(part, bid, tid, lds4);
            if (tid < 8) {
                const int c4 = (bid << 3) + tid;
                const float* cv = scal + SC_C + j*17;
                for (int k = 0; k <= j; ++k) {
                    const float ck = cv[k];
                    const float4 qk = ((const float4*)Qb)[(size_t)k*NC4 + c4];
                    y.x -= ck*qk.x; y.y -= ck*qk.y; y.z -= ck*qk.z; y.w -= ck*qk.w;
                }
                float b2 = y.x*y.x + y.y*y.y + y.z*y.z + y.w*y.w;
                b2 += __shfl_down(b2, 4, 64);
                b2 += __shfl_down(b2, 2, 64);
                b2 += __shfl_down(b2, 1, 64);
                if (tid == 0) atomicAdd(scal + SC_BETA2 + j, b2);
                ((float4*)W)[c4] = y;
            }
        }
        gbar(bcnt, bgen);
    }

    // ===== coeffs = normF * exp(-tau*T) e0 (fp64 Taylor, ||tau*T|| <= ~0.6) =====
    if (bid == 0 && wave == 0) {
        double a = 0.0, bl = 0.0;
        if (lane < LORD)     a  = (double)scal[SC_ALPHA + lane];
        if (lane < LORD - 1) bl = sqrt(fmax((double)scal[SC_BETA2 + lane], 0.0));
        double bprev = __shfl_up(bl, 1, 64);
        if (lane == 0) bprev = 0.0;
        if (lane >= LORD) { a = 0.0; bl = 0.0; bprev = 0.0; }
        double v = (lane == 0) ? 1.0 : 0.0;
        double accd = v;
        for (int n = 1; n <= 30; ++n) {
            double vm = __shfl_up(v, 1, 64);   if (lane == 0)        vm = 0.0;
            double vp = __shfl_down(v, 1, 64); if (lane >= LORD - 1) vp = 0.0;
            const double tv = a*v + bprev*vm + bl*vp;
            v = tv * (-0.08 / (double)n);
            accd += v;
        }
        if (lane < LORD) {
            const float nf = sqrtf(fmaxf(scal[SC_NF2], 0.f));
            scal[SC_COEF + lane] = (float)accd * nf;
        }
    }
    gbar(bcnt, bgen);

    // ===== final: dtheta[p] = (D[p].dir)/(|D[p]|^2 + 1e-4), dir = sum coef_l Q_l
    if (bid < 16) {
        if (tid < LORD) cs[tid] = scal[SC_COEF + tid];
        __syncthreads();
        const float4* D4 = (const float4*)(Dm + (size_t)bid*D_FEAT);
        const float4* Q4 = (const float4*)Qb;
        float num = 0.f, den = 0.f;
        #pragma unroll
        for (int c = 0; c < CPT; ++c) {
            const int i4 = tid + NTHR*c;
            const float4 dv = D4[i4];
            float4 dir = make_float4(0.f, 0.f, 0.f, 0.f);
            #pragma unroll
            for (int l = 0; l < LORD; ++l) {
                const float cl = cs[l];
                const float4 qv = Q4[(size_t)l*NC4 + i4];
                dir.x += cl*qv.x; dir.y += cl*qv.y; dir.z += cl*qv.z; dir.w += cl*qv.w;
            }
            num += dv.x*dir.x + dv.y*dir.y + dv.z*dir.z + dv.w*dir.w;
            den += dv.x*dv.x + dv.y*dv.y + dv.z*dv.z + dv.w*dv.w;
        }
        #pragma unroll
        for (int o = 32; o > 0; o >>= 1) {
            num += __shfl_down(num, o, 64);
            den += __shfl_down(den, o, 64);
        }
        if (lane == 0) { ldsr[wave] = num; ldsr[8 + wave] = den; }
        __syncthreads();
        if (tid == 0) {
            float n = 0.f, d = 0.f;
            #pragma unroll
            for (int w = 0; w < 8; ++w) { n += ldsr[w]; d += ldsr[8 + w]; }
            out[bid] = n / (d + 1e-4f);
        }
    }
}

extern "C" void kernel_launch(void* const* d_in, const int* in_sizes, int n_in,
                              void* d_out, int out_size, void* d_ws, size_t ws_size,
                              hipStream_t stream)
{
    (void)in_sizes; (void)n_in; (void)out_size; (void)ws_size;
    const float* f  = (const float*)d_in[0];
    const float* Rm = (const float*)d_in[1];
    const float* Dm = (const float*)d_in[2];
    float* outp = (float*)d_out;
    float* ws   = (float*)d_ws;
    // zero the scalar/atomic/barrier region (ws is poisoned 0xAA by the harness)
    hipMemsetAsync(ws + OFF_SCAL, 0, SCAL_N * sizeof(float), stream);
    void* args[] = { (void*)&Rm, (void*)&f, (void*)&Dm, (void*)&outp, (void*)&ws };
    hipLaunchCooperativeKernel((const void*)k_all, dim3(NBLK), dim3(NTHR),
                               args, 0, stream);
}

// Round 5
// 901.423 us; speedup vs baseline: 1.3265x; 1.3265x over previous
//
#include <hip/hip_runtime.h>
#include <math.h>

// Problem constants
#define D_FEAT 8192
#define T_RES  2048
#define NC4    2048          // float4 columns
#define LORD   16

// Persistent kernel geometry: 256 blocks x 512 threads, 1 block/CU, 8 rows/block.
#define NTHR   512
#define NBLK   256
#define ROWS   8
#define CPT    4             // float4 per thread (512*4 = 2048 float4 = 8192 floats)

// Workspace layout (float offsets). ~9.1 MB of the 268 MB ws.
#define OFF_Q    0                          // 16 x 8192 Lanczos basis
#define OFF_W    (LORD*D_FEAT)              // unscaled w vector
#define OFF_U    (OFF_W + D_FEAT)           // U[k][t] = (R q_k)_t, 16x2048 (block-local)
#define OFF_PART (OFF_U + LORD*T_RES)       // 256 x 8192 partial y
#define OFF_SCAL (OFF_PART + NBLK*D_FEAT)

#define SC_FF    0
#define SC_FHF   1
#define SC_NF2   2
#define SC_ALPHA 3    // 16
#define SC_BETA2 19   // 16
#define SC_C     35   // 16 steps x 17 slots
#define SC_COEF  307  // 16
#define SC_BAR   324  // 64 barrier counter slots (uint), one per barrier - no reuse
#define SCAL_N   392

// ---- MALL-coherent (agent-scope, cache-bypassing) accessors: sc0 sc1, no wbl2/inv
__device__ __forceinline__ float aload(const float* p) {
    return __hip_atomic_load(p, __ATOMIC_RELAXED, __HIP_MEMORY_SCOPE_AGENT);
}
__device__ __forceinline__ void astore(float* p, float v) {
    __hip_atomic_store(p, v, __ATOMIC_RELAXED, __HIP_MEMORY_SCOPE_AGENT);
}
__device__ __forceinline__ float4 aload4(const float* p) {
    float4 r; r.x = aload(p); r.y = aload(p+1); r.z = aload(p+2); r.w = aload(p+3);
    return r;
}
__device__ __forceinline__ void astore4(float* p, float4 v) {
    astore(p, v.x); astore(p+1, v.y); astore(p+2, v.z); astore(p+3, v.w);
}

// Fence-free device barrier: each barrier has its OWN monotonically-filled slot.
// __syncthreads drains all waves' vmcnt (compiler emits s_waitcnt vmcnt(0) before
// s_barrier), so every sc1 store has reached MALL before the arrive-add.
__device__ __forceinline__ void gbar(unsigned* slots, int idx) {
    __syncthreads();
    if (threadIdx.x == 0) {
        __hip_atomic_fetch_add(&slots[idx], 1u, __ATOMIC_RELAXED,
                               __HIP_MEMORY_SCOPE_AGENT);
        while (__hip_atomic_load(&slots[idx], __ATOMIC_RELAXED,
                                 __HIP_MEMORY_SCOPE_AGENT) < (unsigned)NBLK)
            __builtin_amdgcn_s_sleep(1);
    }
    __syncthreads();
}

// Column reduce: block owns 8 float4 cols (bid*8 .. +8). 64 row-groups x 8 cols.
// Returns reduced float4 for lanes tid<8 (col = tid). Reads via MALL.
__device__ __forceinline__ float4 col_reduce(const float* __restrict__ part,
                                             int bid, int tid, float4* lds4)
{
    const int col = tid & 7, rg = tid >> 3;
    const int c4  = (bid << 3) + col;
    float4 acc = make_float4(0.f, 0.f, 0.f, 0.f);
    #pragma unroll
    for (int i = 0; i < 4; ++i) {
        float4 t = aload4(part + ((size_t)(rg*4 + i)*NC4 + c4)*4);
        acc.x += t.x; acc.y += t.y; acc.z += t.z; acc.w += t.w;
    }
    lds4[tid] = acc;
    __syncthreads();
    float4 a2 = make_float4(0.f, 0.f, 0.f, 0.f);
    if (tid < 64) {
        a2 = lds4[tid];
        #pragma unroll
        for (int i = 1; i < 8; ++i) {
            float4 t = lds4[tid + 64*i];
            a2.x += t.x; a2.y += t.y; a2.z += t.z; a2.w += t.w;
        }
        #pragma unroll
        for (int m = 8; m < 64; m <<= 1) {
            a2.x += __shfl_xor(a2.x, m, 64);
            a2.y += __shfl_xor(a2.y, m, 64);
            a2.z += __shfl_xor(a2.z, m, 64);
            a2.w += __shfl_xor(a2.w, m, 64);
        }
    }
    return a2;
}

__global__ __launch_bounds__(NTHR, 2) void k_all(
    const float* __restrict__ Rm, const float* __restrict__ f,
    const float* __restrict__ Dm, float* __restrict__ out,
    float* __restrict__ ws)
{
    __shared__ float4 lds4[NTHR];
    __shared__ float  ldsr[64];
    __shared__ float  cs[LORD];

    float* Qb   = ws + OFF_Q;
    float* W    = ws + OFF_W;
    float* U    = ws + OFF_U;
    float* part = ws + OFF_PART;
    float* scal = ws + OFF_SCAL;
    unsigned* bars = (unsigned*)(scal + SC_BAR);
    int bar = 0;

    const int tid  = threadIdx.x, bid = blockIdx.x;
    const int wave = tid >> 6,    lane = tid & 63;

    // Load this block's 8 R-rows into registers ONCE (held across all 17 steps).
    const float4* R4 = (const float4*)Rm;
    const size_t  t0 = (size_t)bid * ROWS;
    float4 row[ROWS][CPT];   // 128 regs
    #pragma unroll
    for (int r = 0; r < ROWS; ++r)
        #pragma unroll
        for (int c = 0; c < CPT; ++c)
            row[r][c] = R4[(t0 + r)*NC4 + tid + NTHR*c];

    // ===== INIT phase 1: u = R f ; partials of Hf = -R^T u ; f.f ; f.Hf =====
    {
        const float4* v4 = (const float4*)f;
        float4 q[CPT];
        #pragma unroll
        for (int c = 0; c < CPT; ++c) q[c] = v4[tid + NTHR*c];
        if (bid == 0) {
            float ffp = 0.f;
            #pragma unroll
            for (int c = 0; c < CPT; ++c)
                ffp += q[c].x*q[c].x + q[c].y*q[c].y + q[c].z*q[c].z + q[c].w*q[c].w;
            #pragma unroll
            for (int o = 32; o > 0; o >>= 1) ffp += __shfl_down(ffp, o, 64);
            if (lane == 0) atomicAdd(scal + SC_FF, ffp);
        }
        float s[ROWS];
        #pragma unroll
        for (int r = 0; r < ROWS; ++r) {
            float acc = 0.f;
            #pragma unroll
            for (int c = 0; c < CPT; ++c)
                acc += row[r][c].x*q[c].x + row[r][c].y*q[c].y
                     + row[r][c].z*q[c].z + row[r][c].w*q[c].w;
            s[r] = acc;
        }
        #pragma unroll
        for (int o = 32; o > 0; o >>= 1)
            #pragma unroll
            for (int r = 0; r < ROWS; ++r) s[r] += __shfl_down(s[r], o, 64);
        if (lane == 0) {
            #pragma unroll
            for (int r = 0; r < ROWS; ++r) ldsr[r*8 + wave] = s[r];
        }
        __syncthreads();
        float val = ldsr[lane];
        #pragma unroll
        for (int m = 1; m < 8; m <<= 1) val += __shfl_xor(val, m, 64);
        float u[ROWS];
        #pragma unroll
        for (int r = 0; r < ROWS; ++r) u[r] = __shfl(val, r*8, 64);
        float* p0 = part + ((size_t)bid*NC4)*4;
        #pragma unroll
        for (int c = 0; c < CPT; ++c) {
            float4 y = make_float4(0.f, 0.f, 0.f, 0.f);
            #pragma unroll
            for (int r = 0; r < ROWS; ++r) {
                y.x -= u[r]*row[r][c].x; y.y -= u[r]*row[r][c].y;
                y.z -= u[r]*row[r][c].z; y.w -= u[r]*row[r][c].w;
            }
            astore4(p0 + (size_t)(tid + NTHR*c)*4, y);
        }
        if (tid == 0) {
            float ap = 0.f;
            #pragma unroll
            for (int r = 0; r < ROWS; ++r) ap += u[r]*u[r];
            atomicAdd(scal + SC_FHF, -ap);
        }
    }
    gbar(bars, bar++);

    // ===== INIT phase 2: F = E f - Hf ; W = F ; nf2 =====
    {
        float4 y = col_reduce(part, bid, tid, lds4);
        if (tid < 8) {
            const int c4 = (bid << 3) + tid;
            const float E = aload(scal + SC_FHF) / (aload(scal + SC_FF) + 1e-15f);
            const float4 fv = ((const float4*)f)[c4];
            float4 F = make_float4(E*fv.x - y.x, E*fv.y - y.y,
                                   E*fv.z - y.z, E*fv.w - y.w);
            float n2 = F.x*F.x + F.y*F.y + F.z*F.z + F.w*F.w;
            n2 += __shfl_down(n2, 4, 64);
            n2 += __shfl_down(n2, 2, 64);
            n2 += __shfl_down(n2, 1, 64);
            if (tid == 0) atomicAdd(scal + SC_NF2, n2);
            astore4(W + (size_t)c4*4, F);
        }
    }
    gbar(bars, bar++);

    // ===== Lanczos: 16 steps =====
    for (int j = 0; j < LORD; ++j) {
        // phase 1: q = W/||W|| ; u = R q ; partial y = -u^T rows ; a, c_k atomics
        const float b2prev = (j == 0) ? aload(scal + SC_NF2)
                                      : aload(scal + SC_BETA2 + (j - 1));
        const float scale  = rsqrtf(fmaxf(b2prev, 1e-60f));  // ref: w/max(b,1e-30)
        float4 q[CPT];
        #pragma unroll
        for (int c = 0; c < CPT; ++c) {
            float4 t = aload4(W + (size_t)(tid + NTHR*c)*4);
            t.x *= scale; t.y *= scale; t.z *= scale; t.w *= scale;
            q[c] = t;
        }
        if (bid == 0) {   // publish Q[j]
            float* Qj = Qb + (size_t)j*D_FEAT;
            #pragma unroll
            for (int c = 0; c < CPT; ++c) astore4(Qj + (size_t)(tid + NTHR*c)*4, q[c]);
        }
        float s[ROWS];
        #pragma unroll
        for (int r = 0; r < ROWS; ++r) {
            float acc = 0.f;
            #pragma unroll
            for (int c = 0; c < CPT; ++c)
                acc += row[r][c].x*q[c].x + row[r][c].y*q[c].y
                     + row[r][c].z*q[c].z + row[r][c].w*q[c].w;
            s[r] = acc;
        }
        #pragma unroll
        for (int o = 32; o > 0; o >>= 1)
            #pragma unroll
            for (int r = 0; r < ROWS; ++r) s[r] += __shfl_down(s[r], o, 64);
        if (lane == 0) {
            #pragma unroll
            for (int r = 0; r < ROWS; ++r) ldsr[r*8 + wave] = s[r];
        }
        __syncthreads();
        float val = ldsr[lane];
        #pragma unroll
        for (int m = 1; m < 8; m <<= 1) val += __shfl_xor(val, m, 64);
        if (wave == 0 && (lane & 7) == 0)          // U is block-local: plain store
            U[(size_t)j*T_RES + t0 + (lane >> 3)] = val;
        float u[ROWS];
        #pragma unroll
        for (int r = 0; r < ROWS; ++r) u[r] = __shfl(val, r*8, 64);
        float* p0 = part + ((size_t)bid*NC4)*4;
        #pragma unroll
        for (int c = 0; c < CPT; ++c) {
            float4 y = make_float4(0.f, 0.f, 0.f, 0.f);
            #pragma unroll
            for (int r = 0; r < ROWS; ++r) {
                y.x -= u[r]*row[r][c].x; y.y -= u[r]*row[r][c].y;
                y.z -= u[r]*row[r][c].z; y.w -= u[r]*row[r][c].w;
            }
            astore4(p0 + (size_t)(tid + NTHR*c)*4, y);
        }
        if (tid == 0) {
            float ap = 0.f;
            #pragma unroll
            for (int r = 0; r < ROWS; ++r) ap += u[r]*u[r];
            atomicAdd(scal + SC_ALPHA + j, -ap);
            atomicAdd(scal + SC_C + j*17 + j, -ap);   // c_raw_j = a_j
        }
        if (wave == 0 && lane < j) {   // c_raw_k = Q_k.y = -U_k.u (U block-local)
            float cp = 0.f;
            #pragma unroll
            for (int r = 0; r < ROWS; ++r)
                cp += U[(size_t)lane*T_RES + t0 + r] * u[r];
            atomicAdd(scal + SC_C + j*17 + lane, -cp);
        }
        gbar(bars, bar++);

        if (j == LORD - 1) break;   // beta[15]/w_16 unused by the reference

        // phase 2: w = colsum(part) - sum_{k<=j} c_k Q_k ; beta2[j] = |w|^2
        {
            float4 y = col_reduce(part, bid, tid, lds4);
            if (tid < 8) {
                const int c4 = (bid << 3) + tid;
                const float* cv = scal + SC_C + j*17;
                for (int k = 0; k <= j; ++k) {
                    const float ck = aload(cv + k);
                    const float4 qk = aload4(Qb + ((size_t)k*NC4 + c4)*4);
                    y.x -= ck*qk.x; y.y -= ck*qk.y; y.z -= ck*qk.z; y.w -= ck*qk.w;
                }
                float b2 = y.x*y.x + y.y*y.y + y.z*y.z + y.w*y.w;
                b2 += __shfl_down(b2, 4, 64);
                b2 += __shfl_down(b2, 2, 64);
                b2 += __shfl_down(b2, 1, 64);
                if (tid == 0) atomicAdd(scal + SC_BETA2 + j, b2);
                astore4(W + (size_t)c4*4, y);
            }
        }
        gbar(bars, bar++);
    }

    // ===== coeffs = normF * exp(-tau*T) e0 (fp64 Taylor, ||tau*T|| <= ~0.6) =====
    if (bid == 0 && wave == 0) {
        double a = 0.0, bl = 0.0;
        if (lane < LORD)     a  = (double)aload(scal + SC_ALPHA + lane);
        if (lane < LORD - 1) bl = sqrt(fmax((double)aload(scal + SC_BETA2 + lane), 0.0));
        double bprev = __shfl_up(bl, 1, 64);
        if (lane == 0) bprev = 0.0;
        if (lane >= LORD) { a = 0.0; bl = 0.0; bprev = 0.0; }
        double v = (lane == 0) ? 1.0 : 0.0;
        double accd = v;
        for (int n = 1; n <= 30; ++n) {
            double vm = __shfl_up(v, 1, 64);   if (lane == 0)        vm = 0.0;
            double vp = __shfl_down(v, 1, 64); if (lane >= LORD - 1) vp = 0.0;
            const double tv = a*v + bprev*vm + bl*vp;
            v = tv * (-0.08 / (double)n);
            accd += v;
        }
        if (lane < LORD) {
            const float nf = sqrtf(fmaxf(aload(scal + SC_NF2), 0.f));
            astore(scal + SC_COEF + lane, (float)accd * nf);
        }
    }
    gbar(bars, bar++);

    // ===== final: dtheta[p] = (D[p].dir)/(|D[p]|^2 + 1e-4), dir = sum coef_l Q_l
    if (bid < 16) {
        if (tid < LORD) cs[tid] = aload(scal + SC_COEF + tid);
        __syncthreads();
        const float4* D4 = (const float4*)(Dm + (size_t)bid*D_FEAT);
        float num = 0.f, den = 0.f;
        #pragma unroll
        for (int c = 0; c < CPT; ++c) {
            const int i4 = tid + NTHR*c;
            const float4 dv = D4[i4];
            float4 dir = make_float4(0.f, 0.f, 0.f, 0.f);
            #pragma unroll
            for (int l = 0; l < LORD; ++l) {
                const float cl = cs[l];
                const float4 qv = aload4(Qb + ((size_t)l*NC4 + i4)*4);
                dir.x += cl*qv.x; dir.y += cl*qv.y; dir.z += cl*qv.z; dir.w += cl*qv.w;
            }
            num += dv.x*dir.x + dv.y*dir.y + dv.z*dir.z + dv.w*dir.w;
            den += dv.x*dv.x + dv.y*dv.y + dv.z*dv.z + dv.w*dv.w;
        }
        #pragma unroll
        for (int o = 32; o > 0; o >>= 1) {
            num += __shfl_down(num, o, 64);
            den += __shfl_down(den, o, 64);
        }
        if (lane == 0) { ldsr[wave] = num; ldsr[8 + wave] = den; }
        __syncthreads();
        if (tid == 0) {
            float n = 0.f, d = 0.f;
            #pragma unroll
            for (int w = 0; w < 8; ++w) { n += ldsr[w]; d += ldsr[8 + w]; }
            out[bid] = n / (d + 1e-4f);
        }
    }
}

extern "C" void kernel_launch(void* const* d_in, const int* in_sizes, int n_in,
                              void* d_out, int out_size, void* d_ws, size_t ws_size,
                              hipStream_t stream)
{
    (void)in_sizes; (void)n_in; (void)out_size; (void)ws_size;
    const float* f  = (const float*)d_in[0];
    const float* Rm = (const float*)d_in[1];
    const float* Dm = (const float*)d_in[2];
    float* outp = (float*)d_out;
    float* ws   = (float*)d_ws;
    // zero scalars + barrier slots (ws is poisoned 0xAA by the harness); the fill
    // kernel's end-of-kernel release flushes these zeros to the coherence point.
    hipMemsetAsync(ws + OFF_SCAL, 0, SCAL_N * sizeof(float), stream);
    void* args[] = { (void*)&Rm, (void*)&f, (void*)&Dm, (void*)&outp, (void*)&ws };
    hipLaunchCooperativeKernel((const void*)k_all, dim3(NBLK), dim3(NTHR),
                               args, 0, stream);
}

// Round 7
// 437.402 us; speedup vs baseline: 2.7337x; 2.0609x over previous
//
#include <hip/hip_runtime.h>
#include <math.h>

// Problem constants
#define D_FEAT 8192
#define NC4    2048          // float4 columns per R row
#define T_RES  2048
#define LORD   16

// Geometry: 256 blocks x 512 threads (1 block/CU). Block owns a 32-column slab
// of R (all 2048 rows) in registers: thread (cg=tid&7, rg=tid>>3) holds rows
// rg+64*i (i<32) of float4-column (bid*8+cg). 32 float4 = 128 VGPRs.
#define NTHR 512
#define NBLK 256
#define RPT  32

// Global workspace layout (float offsets). Everything cross-block goes through
// MALL-coherent uncached dword ops; NO float atomics anywhere (determinism).
#define G_B2    0                      // 17 (only 0..15 used)
#define G_FF    17
#define G_COEF  18                     // 16
#define G_BAR   34                     // 64 uint barrier slots (monotone)
#define G_ZEND  98                     // memset extent
#define G_URAW  128                    // 17 x 2048 reduced u vectors (slot16 = R f)
#define G_UP    (G_URAW + 17*2048)     // 256 x 2048 u partials [b][t]
#define G_DP    (G_UP + 256*2048)      // 17 x 256 dot partials [k][b]
#define G_B2P   (G_DP + 17*256)        // 256
#define G_FFP   (G_B2P + 256)          // 256
#define G_NUMP  (G_FFP + 256)          // 16 x 256
#define G_DENP  (G_NUMP + 16*256)      // 16 x 256
#define G_TOTAL (G_DENP + 16*256)

// ---- MALL-coherent (cache-bypassing) accessors — validated R5/R6
__device__ __forceinline__ float aload(const float* p) {
    return __hip_atomic_load(p, __ATOMIC_RELAXED, __HIP_MEMORY_SCOPE_AGENT);
}
__device__ __forceinline__ void astore(float* p, float v) {
    __hip_atomic_store(p, v, __ATOMIC_RELAXED, __HIP_MEMORY_SCOPE_AGENT);
}

// Fence-free device barrier (validated R5): per-barrier dedicated slot;
// __syncthreads drains all waves' vmcnt so sc1 stores are at MALL first.
__device__ __forceinline__ void gbar(unsigned* slots, int idx) {
    __syncthreads();
    if (threadIdx.x == 0) {
        __hip_atomic_fetch_add(&slots[idx], 1u, __ATOMIC_RELAXED,
                               __HIP_MEMORY_SCOPE_AGENT);
        while (__hip_atomic_load(&slots[idx], __ATOMIC_RELAXED,
                                 __HIP_MEMORY_SCOPE_AGENT) < (unsigned)NBLK)
            __builtin_amdgcn_s_sleep(1);
    }
    __syncthreads();
}

__device__ __forceinline__ float wave_sum64(float s) {
    #pragma unroll
    for (int m = 1; m < 64; m <<= 1) s += __shfl_xor(s, m, 64);
    return s;
}

// slab u contribution: for each row t=rg+64i, d = R[t][slab] . w_slab; ubuf[t]=d
__device__ __forceinline__ void u_pass_lds(const float4 (&rr)[RPT],
                                           const float* wsl, float* ubuf,
                                           int rg, int cg) {
    const float4 w4 = ((const float4*)wsl)[cg];
    #pragma unroll
    for (int i = 0; i < RPT; ++i) {
        float d = rr[i].x*w4.x + rr[i].y*w4.y + rr[i].z*w4.z + rr[i].w*w4.w;
        d += __shfl_xor(d, 1, 64);
        d += __shfl_xor(d, 2, 64);
        d += __shfl_xor(d, 4, 64);
        if (cg == 0) ubuf[rg + 64*i] = d;
    }
}

// coalesced uncached flush of block's u contribution: UP[bid][0..2048)
__device__ __forceinline__ void flush_up(float* UP, const float* ubuf,
                                         int bid, int tid) {
    #pragma unroll
    for (int r = 0; r < 4; ++r)
        astore(&UP[(size_t)bid*2048 + tid + 512*r], ubuf[tid + 512*r]);
}

// Deterministic reduce of UP over 256 blocks at this block's 8 owned elements
// (t = 8*bid .. +8). Writes ufin[8], uhrow[8] (LDS) and uraw (global).
__device__ __forceinline__ void reduce_up(const float* UP, float* udst,
                                          float (*red2)[8], float* ufin,
                                          float* uhrow, int bid, int tid) {
    const int t_loc = tid & 7, g = tid >> 3;
    float s = 0.f;
    #pragma unroll
    for (int i = 0; i < 4; ++i)
        s += aload(&UP[(size_t)(4*g + i)*2048 + 8*bid + t_loc]);
    red2[g][t_loc] = s;
    __syncthreads();
    if (tid < 8) {
        float u = 0.f;
        #pragma unroll
        for (int g2 = 0; g2 < 64; ++g2) u += red2[g2][tid];   // fixed order
        ufin[tid] = u;
        uhrow[tid] = u;
        astore(&udst[8*bid + tid], u);
    }
    __syncthreads();
}

// y slab partial: acc = -sum_t u[t]*R[t, my col4] over this thread's 32 rows
__device__ __forceinline__ float4 y_pass(const float4 (&rr)[RPT],
                                         const float* u, int rg) {
    float4 acc = make_float4(0.f, 0.f, 0.f, 0.f);
    #pragma unroll
    for (int i = 0; i < RPT; ++i) {
        const float ut = u[rg + 64*i];
        acc.x -= ut*rr[i].x; acc.y -= ut*rr[i].y;
        acc.z -= ut*rr[i].z; acc.w -= ut*rr[i].w;
    }
    return acc;
}

// Reduce per-thread y partials (over rg) into ysl[32]. Fixed order everywhere.
__device__ __forceinline__ void y_reduce(float4 acc, float (*red)[8][4],
                                         float* ysl, int wave, int lane, int tid) {
    #pragma unroll
    for (int m = 8; m < 64; m <<= 1) {
        acc.x += __shfl_xor(acc.x, m, 64); acc.y += __shfl_xor(acc.y, m, 64);
        acc.z += __shfl_xor(acc.z, m, 64); acc.w += __shfl_xor(acc.w, m, 64);
    }
    if (lane < 8) {
        red[wave][lane][0] = acc.x; red[wave][lane][1] = acc.y;
        red[wave][lane][2] = acc.z; red[wave][lane][3] = acc.w;
    }
    __syncthreads();
    if (tid < 32) {
        const int g = tid >> 2, comp = tid & 3;
        float s = 0.f;
        #pragma unroll
        for (int w = 0; w < 8; ++w) s += red[w][g][comp];
        ysl[g*4 + comp] = s;
    }
    __syncthreads();
}

__global__ __launch_bounds__(NTHR, 2) void k_all(
    const float* __restrict__ Rm, const float* __restrict__ f,
    const float* __restrict__ Dm, float* __restrict__ out,
    float* __restrict__ ws)
{
    __shared__ __align__(16) float ubuf[2048];     // 8 KB staging
    __shared__ float red2[64][8];
    __shared__ float red[8][8][4];
    __shared__ float ufin[8];
    __shared__ float uh[17][8];                    // this block's u history slice
    __shared__ __align__(16) float ysl[32];
    __shared__ __align__(16) float dirs[32];
    __shared__ __align__(16) float fsl[32];
    __shared__ float Wh[LORD][32];                 // W slab history (unnormalized)
    __shared__ float bh[LORD];                     // b_j = sqrt(|W_j|^2)
    __shared__ float alph[LORD];
    __shared__ float dotl[LORD];
    __shared__ float cf[LORD];
    __shared__ float misc[2];

    float* b2g  = ws + G_B2;
    float* ffg  = ws + G_FF;
    float* coefg= ws + G_COEF;
    unsigned* bars = (unsigned*)(ws + G_BAR);
    float* uraw = ws + G_URAW;
    float* UP   = ws + G_UP;
    float* DP   = ws + G_DP;
    float* B2P  = ws + G_B2P;
    float* FFP  = ws + G_FFP;
    float* NUMP = ws + G_NUMP;
    float* DENP = ws + G_DENP;
    int bar = 0;

    const int tid = threadIdx.x, bid = blockIdx.x;
    const int cg = tid & 7, rg = tid >> 3;
    const int lane = tid & 63, wave = tid >> 6;

    // Load R column-slab into registers ONCE.
    const float4* R4 = (const float4*)Rm;
    float4 rr[RPT];
    #pragma unroll
    for (int i = 0; i < RPT; ++i)
        rr[i] = R4[(size_t)(rg + 64*i)*NC4 + (bid << 3) + cg];

    // ===== I1: f slab -> LDS ; FFP partial ; u_init partials =====
    if (wave == 0) {
        float4 fv = make_float4(0.f, 0.f, 0.f, 0.f);
        if (lane < 8) { fv = ((const float4*)f)[(bid << 3) + lane];
                        ((float4*)fsl)[lane] = fv; }
        float s2 = fv.x*fv.x + fv.y*fv.y + fv.z*fv.z + fv.w*fv.w;
        s2 += __shfl_xor(s2, 1, 64);
        s2 += __shfl_xor(s2, 2, 64);
        s2 += __shfl_xor(s2, 4, 64);
        if (lane == 0) astore(&FFP[bid], s2);
    }
    __syncthreads();
    u_pass_lds(rr, fsl, ubuf, rg, cg);
    __syncthreads();
    flush_up(UP, ubuf, bid, tid);
    gbar(bars, bar++);

    // ===== I2: reduce UP -> uraw[16]=Rf ; uu partial ; block0: FFP -> ffg =====
    reduce_up(UP, uraw + 16*2048, red2, ufin, uh[16], bid, tid);
    if (tid == 0) {
        float pd = 0.f;
        #pragma unroll
        for (int t = 0; t < 8; ++t) pd += ufin[t]*ufin[t];
        astore(&DP[16*256 + bid], pd);
    }
    if (bid == 0 && wave == 1) {
        float s = 0.f;
        #pragma unroll
        for (int i = 0; i < 4; ++i) s += aload(&FFP[lane + 64*i]);
        s = wave_sum64(s);
        if (lane == 0) astore(ffg, s);
    }
    gbar(bars, bar++);

    // ===== I3: uu reduce (all blocks, identical) ; y=Hf slab ; W0 ; u partials
    if (wave == 0) {
        float s = 0.f;
        #pragma unroll
        for (int i = 0; i < 4; ++i) s += aload(&DP[16*256 + lane + 64*i]);
        s = wave_sum64(s);
        if (lane == 0) { misc[1] = s; misc[0] = aload(ffg); }
    }
    #pragma unroll
    for (int r = 0; r < 4; ++r)
        ubuf[tid + 512*r] = aload(&uraw[16*2048 + tid + 512*r]);
    __syncthreads();
    {
        float4 acc = y_pass(rr, ubuf, rg);
        y_reduce(acc, red, ysl, wave, lane, tid);
        const float E = -misc[1] / (misc[0] + 1e-15f);
        float v = 0.f;
        if (tid < 32) { v = E*fsl[tid] - ysl[tid]; Wh[0][tid] = v; }
        if (wave == 0) {
            float s = (lane < 32) ? v*v : 0.f;
            s = wave_sum64(s);
            if (lane == 0) astore(&B2P[bid], s);
        }
        __syncthreads();
        u_pass_lds(rr, Wh[0], ubuf, rg, cg);
        __syncthreads();
        flush_up(UP, ubuf, bid, tid);
    }
    gbar(bars, bar++);

    // ===== Lanczos steps j=0..15 =====
    for (int j = 0; j < LORD; ++j) {
        // --- Phase 1: reduce u partials; dot partials vs history; b2[j] ---
        reduce_up(UP, uraw + (size_t)j*2048, red2, ufin, uh[j], bid, tid);
        if (wave == 0 && lane <= j) {
            float pd = 0.f;
            #pragma unroll 1
            for (int t = 0; t < 8; ++t) pd += ufin[t] * uh[lane][t];
            astore(&DP[lane*256 + bid], pd);
        }
        if (bid == 0 && wave == 1) {
            float s = 0.f;
            #pragma unroll
            for (int i = 0; i < 4; ++i) s += aload(&B2P[lane + 64*i]);
            s = wave_sum64(s);
            if (lane == 0) astore(&b2g[j], s);
        }
        gbar(bars, bar++);

        // --- Phase 2: dots (all blocks, identical); y; W_{j+1}; u partials ---
        if (tid == 0) misc[0] = aload(&b2g[j]);
        for (int k = wave; k <= j; k += 8) {
            float s = 0.f;
            #pragma unroll
            for (int i = 0; i < 4; ++i) s += aload(&DP[k*256 + lane + 64*i]);
            s = wave_sum64(s);
            if (lane == 0) dotl[k] = s;
        }
        __syncthreads();
        const float b2j = misc[0];
        const float bj  = sqrtf(fmaxf(b2j, 1e-60f));   // ref: w/max(b,1e-30)
        if (tid == 0) {
            bh[j]   = bj;
            alph[j] = -dotl[j] / fmaxf(b2j, 1e-60f);
        }
        if (j < LORD - 1) {
            const float inv = 1.0f / bj;
            #pragma unroll
            for (int r = 0; r < 4; ++r)
                ubuf[tid + 512*r] =
                    aload(&uraw[(size_t)j*2048 + tid + 512*r]) * inv;
            __syncthreads();
            float4 acc = y_pass(rr, ubuf, rg);
            y_reduce(acc, red, ysl, wave, lane, tid);
            // W_{j+1} = y + sum_{k<=j} dot_jk/(b_j b_k^2) W_k  (== full reorth)
            float v = 0.f;
            if (tid < 32) {
                v = ysl[tid];
                for (int k = 0; k <= j; ++k)
                    v += (dotl[k] / (bj * bh[k] * bh[k])) * Wh[k][tid];
                Wh[j+1][tid] = v;
            }
            if (wave == 0) {
                float s = (lane < 32) ? v*v : 0.f;
                s = wave_sum64(s);
                if (lane == 0) astore(&B2P[bid], s);
            }
            __syncthreads();
            u_pass_lds(rr, Wh[j+1], ubuf, rg, cg);
            __syncthreads();
            flush_up(UP, ubuf, bid, tid);
        } else {
            __syncthreads();   // alph[15]/bh[15] visible
            // coeffs = normF * exp(-tau*T) e0 via fp64 Taylor (block 0)
            if (bid == 0 && wave == 0) {
                double a = 0.0, bl = 0.0;
                if (lane < LORD)     a  = (double)alph[lane];
                if (lane < LORD - 1) bl = (double)bh[lane + 1];
                double bprev = __shfl_up(bl, 1, 64);
                if (lane == 0) bprev = 0.0;
                if (lane >= LORD) { a = 0.0; bl = 0.0; bprev = 0.0; }
                double v = (lane == 0) ? 1.0 : 0.0;
                double accd = v;
                for (int n = 1; n <= 30; ++n) {
                    double vm = __shfl_up(v, 1, 64);
                    if (lane == 0) vm = 0.0;
                    double vp = __shfl_down(v, 1, 64);
                    if (lane >= LORD - 1) vp = 0.0;
                    const double tv = a*v + bprev*vm + bl*vp;
                    v = tv * (-0.08 / (double)n);
                    accd += v;
                }
                if (lane < LORD)
                    astore(&coefg[lane], (float)accd * bh[0]);
            }
        }
        gbar(bars, bar++);
    }

    // ===== F1: dir slab from LDS W history ; num/den partials =====
    if (wave == 0 && lane < 16) cf[lane] = aload(&coefg[lane]);
    __syncthreads();
    if (tid < 32) {
        float s = 0.f;
        #pragma unroll
        for (int l = 0; l < LORD; ++l) s += cf[l] * Wh[l][tid] / bh[l];
        dirs[tid] = s;
    }
    __syncthreads();
    if (wave == 0 && lane < 16) {
        const float4* Dp = (const float4*)Dm + (size_t)lane*NC4 + (bid << 3);
        float num = 0.f, den = 0.f;
        #pragma unroll
        for (int g = 0; g < 8; ++g) {
            const float4 dv = Dp[g];
            const float4 dr = ((const float4*)dirs)[g];
            num += dv.x*dr.x + dv.y*dr.y + dv.z*dr.z + dv.w*dr.w;
            den += dv.x*dv.x + dv.y*dv.y + dv.z*dv.z + dv.w*dv.w;
        }
        astore(&NUMP[lane*256 + bid], num);
        astore(&DENP[lane*256 + bid], den);
    }
    gbar(bars, bar++);

    // ===== F2: block 0 reduces num/den deterministically, writes out =====
    if (bid == 0) {
        for (int p = wave; p < 16; p += 8) {
            float n = 0.f, d = 0.f;
            #pragma unroll
            for (int i = 0; i < 4; ++i) {
                n += aload(&NUMP[p*256 + lane + 64*i]);
                d += aload(&DENP[p*256 + lane + 64*i]);
            }
            n = wave_sum64(n);
            d = wave_sum64(d);
            if (lane == 0) out[p] = n / (d + 1e-4f);
        }
    }
}

extern "C" void kernel_launch(void* const* d_in, const int* in_sizes, int n_in,
                              void* d_out, int out_size, void* d_ws, size_t ws_size,
                              hipStream_t stream)
{
    (void)in_sizes; (void)n_in; (void)out_size; (void)ws_size;
    const float* f  = (const float*)d_in[0];
    const float* Rm = (const float*)d_in[1];
    const float* Dm = (const float*)d_in[2];
    float* outp = (float*)d_out;
    float* ws   = (float*)d_ws;
    // Zero scalars + barrier slots only (all other arrays are fully written
    // before first read; ws is poisoned 0xAA by the harness each launch).
    hipMemsetAsync(ws, 0, G_ZEND * sizeof(float), stream);
    void* args[] = { (void*)&Rm, (void*)&f, (void*)&Dm, (void*)&outp, (void*)&ws };
    hipLaunchCooperativeKernel((const void*)k_all, dim3(NBLK), dim3(NTHR),
                               args, 0, stream);
}

// Round 8
// 333.872 us; speedup vs baseline: 3.5814x; 1.3101x over previous
//
#include <hip/hip_runtime.h>
#include <math.h>

// Problem constants
#define D_FEAT 8192
#define NC4    2048          // float4 columns per R row
#define T_RES  2048
#define LORD   16

// Geometry: 256 blocks x 512 threads (1 block/CU). Block owns a 32-column slab
// of R (all 2048 rows) in registers: thread (cg=tid&7, rg=tid>>3) holds rows
// rg+64*i (i<32) of float4-column (bid*8+cg). 32 float4 = 128 VGPRs.
#define NTHR 512
#define NBLK 256
#define RPT  32
#define NBAR 40

// Global workspace layout (float offsets). All cross-block data moves through
// MALL-coherent uncached dword ops; NO float atomics anywhere (determinism).
#define G_COEF 0                       // 16
#define G_BAR  16                      // NBAR x 64 uint arrive counters
#define G_REL  (G_BAR + NBAR*64)       // NBAR uint release words
#define G_ZEND (G_REL + NBAR)          // memset extent
#define G_URAW 2688                    // 17 x 2048 reduced u vectors (slot16 = R f)
#define G_UP   (G_URAW + 17*2048)      // 256 chunks x 256 blocks x 8 els
#define G_DP   (G_UP + 256*2048)       // 17 x 256 dot partials [k][b]
#define G_B2P  (G_DP + 17*256)         // 256
#define G_FFP  (G_B2P + 256)           // 256
#define G_NUMP (G_FFP + 256)           // 16 x 256
#define G_DENP (G_NUMP + 16*256)       // 16 x 256

// ---- MALL-coherent (cache-bypassing) accessors — validated R5/R7
__device__ __forceinline__ float aload(const float* p) {
    return __hip_atomic_load(p, __ATOMIC_RELAXED, __HIP_MEMORY_SCOPE_AGENT);
}
__device__ __forceinline__ void astore(float* p, float v) {
    __hip_atomic_store(p, v, __ATOMIC_RELAXED, __HIP_MEMORY_SCOPE_AGENT);
}
__device__ __forceinline__ unsigned aloadu(const unsigned* p) {
    return __hip_atomic_load(p, __ATOMIC_RELAXED, __HIP_MEMORY_SCOPE_AGENT);
}

// Tree barrier: arrive on 64 counters (4 blocks each), block0-wave0 polls the
// counters and publishes a release word; all others poll only the release word.
// __syncthreads drains vmcnt so all sc1 stores are at MALL before arrive.
__device__ __forceinline__ void gbar(unsigned* slots, unsigned* rel,
                                     int idx, int bid) {
    __syncthreads();
    const int tid = threadIdx.x;
    if (tid == 0)
        __hip_atomic_fetch_add(&slots[idx*64 + (bid & 63)], 1u,
                               __ATOMIC_RELAXED, __HIP_MEMORY_SCOPE_AGENT);
    if (bid == 0 && tid < 64) {
        while (aloadu(&slots[idx*64 + tid]) < 4u)
            __builtin_amdgcn_s_sleep(1);
        if (tid == 0)
            __hip_atomic_store(&rel[idx], 1u, __ATOMIC_RELAXED,
                               __HIP_MEMORY_SCOPE_AGENT);
    } else if (tid == 0) {
        while (aloadu(&rel[idx]) == 0u)
            __builtin_amdgcn_s_sleep(1);
    }
    __syncthreads();
}

__device__ __forceinline__ float wave_sum64(float s) {
    #pragma unroll
    for (int m = 1; m < 64; m <<= 1) s += __shfl_xor(s, m, 64);
    return s;
}

// slab u contribution: for each row t=rg+64i, d = R[t][slab] . w_slab; ubuf[t]=d
__device__ __forceinline__ void u_pass_lds(const float4 (&rr)[RPT],
                                           const float* wsl, float* ubuf,
                                           int rg, int cg) {
    const float4 w4 = ((const float4*)wsl)[cg];
    #pragma unroll
    for (int i = 0; i < RPT; ++i) {
        float d = rr[i].x*w4.x + rr[i].y*w4.y + rr[i].z*w4.z + rr[i].w*w4.w;
        d += __shfl_xor(d, 1, 64);
        d += __shfl_xor(d, 2, 64);
        d += __shfl_xor(d, 4, 64);
        if (cg == 0) ubuf[rg + 64*i] = d;
    }
}

// flush block's u contribution in chunked layout: UP2[t>>3][bid][t&7].
// 8 consecutive lanes write one 32B chunk-slot -> 8 segments/instr.
__device__ __forceinline__ void flush_up2(float* UP2, const float* ubuf,
                                          int bid, int tid) {
    #pragma unroll
    for (int r = 0; r < 4; ++r) {
        const int t = tid + 512*r;
        astore(&UP2[(size_t)(t >> 3)*2048 + bid*8 + (tid & 7)], ubuf[t]);
    }
}

// Deterministic reduce at this block's owned chunk (t=8*bid..+8): contiguous
// 8KB read. Writes ufin[8], uhrow[8] (LDS) and uraw[8*bid..] (global).
__device__ __forceinline__ void reduce_up2(const float* UP2, float* udst,
                                           float (*red2)[8], float* ufin,
                                           float* uhrow, int bid, int tid) {
    const int off = tid & 7, g = tid >> 3;
    const float* base = UP2 + (size_t)bid*2048;
    float s = 0.f;
    #pragma unroll
    for (int i = 0; i < 4; ++i) s += aload(base + (4*g + i)*8 + off);
    red2[g][off] = s;
    __syncthreads();
    if (tid < 8) {
        float u = 0.f;
        #pragma unroll
        for (int g2 = 0; g2 < 64; ++g2) u += red2[g2][tid];   // fixed order
        ufin[tid] = u;
        uhrow[tid] = u;
        astore(&udst[8*bid + tid], u);
    }
    __syncthreads();
}

// y slab partial: acc = -sum_t u[t]*R[t, my col4] over this thread's 32 rows
__device__ __forceinline__ float4 y_pass(const float4 (&rr)[RPT],
                                         const float* u, int rg) {
    float4 acc = make_float4(0.f, 0.f, 0.f, 0.f);
    #pragma unroll
    for (int i = 0; i < RPT; ++i) {
        const float ut = u[rg + 64*i];
        acc.x -= ut*rr[i].x; acc.y -= ut*rr[i].y;
        acc.z -= ut*rr[i].z; acc.w -= ut*rr[i].w;
    }
    return acc;
}

// Reduce per-thread y partials (over rg) into ysl[32]. Fixed order everywhere.
__device__ __forceinline__ void y_reduce(float4 acc, float (*red)[8][4],
                                         float* ysl, int wave, int lane, int tid) {
    #pragma unroll
    for (int m = 8; m < 64; m <<= 1) {
        acc.x += __shfl_xor(acc.x, m, 64); acc.y += __shfl_xor(acc.y, m, 64);
        acc.z += __shfl_xor(acc.z, m, 64); acc.w += __shfl_xor(acc.w, m, 64);
    }
    if (lane < 8) {
        red[wave][lane][0] = acc.x; red[wave][lane][1] = acc.y;
        red[wave][lane][2] = acc.z; red[wave][lane][3] = acc.w;
    }
    __syncthreads();
    if (tid < 32) {
        const int g = tid >> 2, comp = tid & 3;
        float s = 0.f;
        #pragma unroll
        for (int w = 0; w < 8; ++w) s += red[w][g][comp];
        ysl[g*4 + comp] = s;
    }
    __syncthreads();
}

__global__ __launch_bounds__(NTHR, 2) void k_all(
    const float* __restrict__ Rm, const float* __restrict__ f,
    const float* __restrict__ Dm, float* __restrict__ out,
    float* __restrict__ ws)
{
    __shared__ __align__(16) float ubuf[2048];
    __shared__ float red2[64][8];
    __shared__ float red[8][8][4];
    __shared__ float ufin[8];
    __shared__ float uh[17][8];
    __shared__ __align__(16) float ysl[32];
    __shared__ __align__(16) float dirs[32];
    __shared__ __align__(16) float fsl[32];
    __shared__ float Wh[LORD][32];
    __shared__ float bh[LORD];
    __shared__ float alph[LORD];
    __shared__ float dotl[LORD];
    __shared__ float cf[LORD];
    __shared__ float misc[4];   // [0]=b2j  [2]=ff  [3]=uu

    float* coefg  = ws + G_COEF;
    unsigned* bars = (unsigned*)(ws + G_BAR);
    unsigned* rel  = (unsigned*)(ws + G_REL);
    float* uraw = ws + G_URAW;
    float* UP2  = ws + G_UP;
    float* DP   = ws + G_DP;
    float* B2P  = ws + G_B2P;
    float* FFP  = ws + G_FFP;
    float* NUMP = ws + G_NUMP;
    float* DENP = ws + G_DENP;
    int bar = 0;

    const int tid = threadIdx.x, bid = blockIdx.x;
    const int cg = tid & 7, rg = tid >> 3;
    const int lane = tid & 63, wave = tid >> 6;

    // Load R column-slab into registers ONCE.
    const float4* R4 = (const float4*)Rm;
    float4 rr[RPT];
    #pragma unroll
    for (int i = 0; i < RPT; ++i)
        rr[i] = R4[(size_t)(rg + 64*i)*NC4 + (bid << 3) + cg];

    // ===== I1: f slab -> LDS ; FFP partial ; u_init partials =====
    if (wave == 0) {
        float4 fv = make_float4(0.f, 0.f, 0.f, 0.f);
        if (lane < 8) { fv = ((const float4*)f)[(bid << 3) + lane];
                        ((float4*)fsl)[lane] = fv; }
        float s2 = fv.x*fv.x + fv.y*fv.y + fv.z*fv.z + fv.w*fv.w;
        s2 += __shfl_xor(s2, 1, 64);
        s2 += __shfl_xor(s2, 2, 64);
        s2 += __shfl_xor(s2, 4, 64);
        if (lane == 0) astore(&FFP[bid], s2);
    }
    __syncthreads();
    u_pass_lds(rr, fsl, ubuf, rg, cg);
    __syncthreads();
    flush_up2(UP2, ubuf, bid, tid);
    gbar(bars, rel, bar++, bid);

    // ===== I2: reduce UP2 -> uraw[16]=Rf ; uu partial ; ff all-blocks reduce =====
    reduce_up2(UP2, uraw + 16*2048, red2, ufin, uh[16], bid, tid);
    if (tid == 0) {
        float pd = 0.f;
        #pragma unroll
        for (int t = 0; t < 8; ++t) pd += ufin[t]*ufin[t];
        astore(&DP[16*256 + bid], pd);
    }
    if (wave == 1) {   // every block reduces FFP identically (fixed order)
        float s = 0.f;
        #pragma unroll
        for (int i = 0; i < 4; ++i) s += aload(&FFP[lane + 64*i]);
        s = wave_sum64(s);
        if (lane == 0) misc[2] = s;
    }
    gbar(bars, rel, bar++, bid);

    // ===== I3: uu reduce (all blocks) ; y=Hf ; W0 ; b2 partial ; u(W0) =====
    if (wave == 0) {
        float s = 0.f;
        #pragma unroll
        for (int i = 0; i < 4; ++i) s += aload(&DP[16*256 + lane + 64*i]);
        s = wave_sum64(s);
        if (lane == 0) misc[3] = s;
    }
    #pragma unroll
    for (int r = 0; r < 4; ++r)
        ubuf[tid + 512*r] = aload(&uraw[16*2048 + tid + 512*r]);
    __syncthreads();
    {
        float4 acc = y_pass(rr, ubuf, rg);
        y_reduce(acc, red, ysl, wave, lane, tid);
        const float E = -misc[3] / (misc[2] + 1e-15f);
        float v = 0.f;
        if (tid < 32) { v = E*fsl[tid] - ysl[tid]; Wh[0][tid] = v; }
        if (wave == 0) {
            float s = (lane < 32) ? v*v : 0.f;
            s = wave_sum64(s);
            if (lane == 0) astore(&B2P[bid], s);
        }
        __syncthreads();
        u_pass_lds(rr, Wh[0], ubuf, rg, cg);
        __syncthreads();
        flush_up2(UP2, ubuf, bid, tid);
    }
    gbar(bars, rel, bar++, bid);

    // ===== Lanczos steps j=0..15 =====
    for (int j = 0; j < LORD; ++j) {
        // --- Phase 1: reduce u ; dot partials vs history ; b2 all-blocks ---
        reduce_up2(UP2, uraw + (size_t)j*2048, red2, ufin, uh[j], bid, tid);
        if (wave == 0 && lane <= j) {
            float pd = 0.f;
            #pragma unroll 1
            for (int t = 0; t < 8; ++t) pd += ufin[t] * uh[lane][t];
            astore(&DP[lane*256 + bid], pd);
        }
        if (wave == 1) {   // every block reduces B2P identically
            float s = 0.f;
            #pragma unroll
            for (int i = 0; i < 4; ++i) s += aload(&B2P[lane + 64*i]);
            s = wave_sum64(s);
            if (lane == 0) misc[0] = s;
        }
        gbar(bars, rel, bar++, bid);

        // --- Phase 2: u broadcast (early issue); dots reduce; y; W_{j+1} ---
        float tmp[4];
        if (j < LORD - 1) {
            #pragma unroll
            for (int r = 0; r < 4; ++r)
                tmp[r] = aload(&uraw[(size_t)j*2048 + tid + 512*r]);
        }
        for (int k = wave; k <= j; k += 8) {
            float s = 0.f;
            #pragma unroll
            for (int i = 0; i < 4; ++i) s += aload(&DP[k*256 + lane + 64*i]);
            s = wave_sum64(s);
            if (lane == 0) dotl[k] = s;
        }
        __syncthreads();
        const float b2j = misc[0];
        const float bj  = sqrtf(fmaxf(b2j, 1e-60f));   // ref: w/max(b,1e-30)
        if (tid == 0) {
            bh[j]   = bj;
            alph[j] = -dotl[j] / fmaxf(b2j, 1e-60f);
        }
        if (j < LORD - 1) {
            const float inv = 1.0f / bj;
            #pragma unroll
            for (int r = 0; r < 4; ++r) ubuf[tid + 512*r] = tmp[r] * inv;
            __syncthreads();
            float4 acc = y_pass(rr, ubuf, rg);
            y_reduce(acc, red, ysl, wave, lane, tid);
            // W_{j+1} = y + sum_{k<=j} dot_jk/(b_j b_k^2) W_k  (full reorth)
            float v = 0.f;
            if (tid < 32) {
                v = ysl[tid];
                for (int k = 0; k <= j; ++k)
                    v += (dotl[k] / (bj * bh[k] * bh[k])) * Wh[k][tid];
                Wh[j+1][tid] = v;
            }
            if (wave == 0) {
                float s = (lane < 32) ? v*v : 0.f;
                s = wave_sum64(s);
                if (lane == 0) astore(&B2P[bid], s);
            }
            __syncthreads();
            u_pass_lds(rr, Wh[j+1], ubuf, rg, cg);
            __syncthreads();
            flush_up2(UP2, ubuf, bid, tid);
        } else {
            __syncthreads();   // alph[15]/bh[15] visible
            // coeffs = normF * exp(-tau*T) e0 via fp64 Taylor (block 0)
            if (bid == 0 && wave == 0) {
                double a = 0.0, bl = 0.0;
                if (lane < LORD)     a  = (double)alph[lane];
                if (lane < LORD - 1) bl = (double)bh[lane + 1];
                double bprev = __shfl_up(bl, 1, 64);
                if (lane == 0) bprev = 0.0;
                if (lane >= LORD) { a = 0.0; bl = 0.0; bprev = 0.0; }
                double v = (lane == 0) ? 1.0 : 0.0;
                double accd = v;
                for (int n = 1; n <= 30; ++n) {
                    double vm = __shfl_up(v, 1, 64);
                    if (lane == 0) vm = 0.0;
                    double vp = __shfl_down(v, 1, 64);
                    if (lane >= LORD - 1) vp = 0.0;
                    const double tv = a*v + bprev*vm + bl*vp;
                    v = tv * (-0.08 / (double)n);
                    accd += v;
                }
                if (lane < LORD)
                    astore(&coefg[lane], (float)accd * bh[0]);
            }
        }
        gbar(bars, rel, bar++, bid);
    }

    // ===== F1: dir slab from LDS W history ; num/den partials =====
    if (wave == 0 && lane < 16) cf[lane] = aload(&coefg[lane]);
    __syncthreads();
    if (tid < 32) {
        float s = 0.f;
        #pragma unroll
        for (int l = 0; l < LORD; ++l) s += cf[l] * Wh[l][tid] / bh[l];
        dirs[tid] = s;
    }
    __syncthreads();
    if (wave == 0 && lane < 16) {
        const float4* Dp = (const float4*)Dm + (size_t)lane*NC4 + (bid << 3);
        float num = 0.f, den = 0.f;
        #pragma unroll
        for (int g = 0; g < 8; ++g) {
            const float4 dv = Dp[g];
            const float4 dr = ((const float4*)dirs)[g];
            num += dv.x*dr.x + dv.y*dr.y + dv.z*dr.z + dv.w*dr.w;
            den += dv.x*dv.x + dv.y*dv.y + dv.z*dv.z + dv.w*dv.w;
        }
        astore(&NUMP[lane*256 + bid], num);
        astore(&DENP[lane*256 + bid], den);
    }
    gbar(bars, rel, bar++, bid);

    // ===== F2: block 0 reduces num/den deterministically, writes out =====
    if (bid == 0) {
        for (int p = wave; p < 16; p += 8) {
            float n = 0.f, d = 0.f;
            #pragma unroll
            for (int i = 0; i < 4; ++i) {
                n += aload(&NUMP[p*256 + lane + 64*i]);
                d += aload(&DENP[p*256 + lane + 64*i]);
            }
            n = wave_sum64(n);
            d = wave_sum64(d);
            if (lane == 0) out[p] = n / (d + 1e-4f);
        }
    }
}

extern "C" void kernel_launch(void* const* d_in, const int* in_sizes, int n_in,
                              void* d_out, int out_size, void* d_ws, size_t ws_size,
                              hipStream_t stream)
{
    (void)in_sizes; (void)n_in; (void)out_size; (void)ws_size;
    const float* f  = (const float*)d_in[0];
    const float* Rm = (const float*)d_in[1];
    const float* Dm = (const float*)d_in[2];
    float* outp = (float*)d_out;
    float* ws   = (float*)d_ws;
    // Zero barrier counters/release words (+coef slot); all other arrays are
    // fully written before first read each launch.
    hipMemsetAsync(ws, 0, G_ZEND * sizeof(float), stream);
    void* args[] = { (void*)&Rm, (void*)&f, (void*)&Dm, (void*)&outp, (void*)&ws };
    hipLaunchCooperativeKernel((const void*)k_all, dim3(NBLK), dim3(NTHR),
                               args, 0, stream);
}

// Round 9
// 309.971 us; speedup vs baseline: 3.8575x; 1.0771x over previous
//
#include <hip/hip_runtime.h>
#include <math.h>

// Problem constants
#define D_FEAT 8192
#define NC4    2048          // float4 columns per R row
#define T_RES  2048
#define LORD   16

// Geometry: 256 blocks x 512 threads (1 block/CU). Block owns a 32-column slab
// of R (all 2048 rows) in registers: thread (cg=tid&7, rg=tid>>3) holds rows
// rg+64*i (i<32) of float4-column (bid*8+cg). 32 float4 = 128 regs.
#define NTHR 512
#define NBLK 256
#define RPT  32
#define NBAR 40
#define LPAD 16            // dwords per 64B line (1 sync word per line)

// ---- Global workspace layout (float offsets) ----
// Zeroed region: coef + padded barrier counters + padded release words.
#define G_COEF  0                        // 16
#define G_BARC  16                       // NBAR*64 counters, LPAD stride
#define G_RELW  (G_BARC + NBAR*64*LPAD)  // NBAR*64 release words, LPAD stride
#define G_ZEND  (G_RELW + NBAR*64*LPAD)
// Rotated single-write-then-single-read regions (cached reads safe):
#define G_URAW  G_ZEND                   // 17 x 2048 reduced u (slot16 = R f)
#define G_UUP   (G_URAW + 17*2048)       // 256 |u_init|^2 partials
#define G_FFP   (G_UUP + 256)            // 256 f.f partials
#define G_B2P   (G_FFP + 256)            // 16 x 256 b2 partials (slot j)
#define G_DP    (G_B2P + 16*256)         // 16 x 17 x 256 dot partials (slot j)
#define G_NUMP  (G_DP + 16*17*256)       // 16 x 256
#define G_DENP  (G_NUMP + 16*256)        // 16 x 256
#define G_UPB   ((G_DENP + 16*256 + 1023) & ~1023)  // 17 slots x 256x2048 u partials

// ---- MALL-coherent uncached ops (writes + sync polling) — validated R5-R8
__device__ __forceinline__ void astore(float* p, float v) {
    __hip_atomic_store(p, v, __ATOMIC_RELAXED, __HIP_MEMORY_SCOPE_AGENT);
}
__device__ __forceinline__ unsigned aloadu(const unsigned* p) {
    return __hip_atomic_load(p, __ATOMIC_RELAXED, __HIP_MEMORY_SCOPE_AGENT);
}

// Contention-free tree barrier: 64 arrive counters (4 blocks each) and 64
// release words, every sync word on its own 64B line. block0 wave0 observes all
// counters, then its 64 lanes store 64 release words; each block polls the word
// matching (bid&63) -> <=4 pollers per line. __syncthreads drains vmcnt so all
// uncached payload stores are at MALL before the arrive RMW issues.
__device__ __forceinline__ void gbar(unsigned* cnt, unsigned* rel,
                                     int idx, int bid) {
    __syncthreads();
    const int tid = threadIdx.x;
    if (tid == 0)
        __hip_atomic_fetch_add(&cnt[(idx*64 + (bid & 63))*LPAD], 1u,
                               __ATOMIC_RELAXED, __HIP_MEMORY_SCOPE_AGENT);
    if (bid == 0) {
        if (tid < 64) {
            while (aloadu(&cnt[(idx*64 + tid)*LPAD]) < 4u)
                __builtin_amdgcn_s_sleep(1);
            // wave reconverged => all 64 counters full => broadcast release
            __hip_atomic_store(&rel[(idx*64 + tid)*LPAD], 1u,
                               __ATOMIC_RELAXED, __HIP_MEMORY_SCOPE_AGENT);
        }
    } else if (tid == 0) {
        while (aloadu(&rel[(idx*64 + (bid & 63))*LPAD]) == 0u)
            __builtin_amdgcn_s_sleep(1);
    }
    __syncthreads();
}

__device__ __forceinline__ float wave_sum64(float s) {
    #pragma unroll
    for (int m = 1; m < 64; m <<= 1) s += __shfl_xor(s, m, 64);
    return s;
}

// slab u contribution: for each row t=rg+64i, d = R[t][slab] . w_slab; ubuf[t]=d
__device__ __forceinline__ void u_pass_lds(const float4 (&rr)[RPT],
                                           const float* wsl, float* ubuf,
                                           int rg, int cg) {
    const float4 w4 = ((const float4*)wsl)[cg];
    #pragma unroll
    for (int i = 0; i < RPT; ++i) {
        float d = rr[i].x*w4.x + rr[i].y*w4.y + rr[i].z*w4.z + rr[i].w*w4.w;
        d += __shfl_xor(d, 1, 64);
        d += __shfl_xor(d, 2, 64);
        d += __shfl_xor(d, 4, 64);
        if (cg == 0) ubuf[rg + 64*i] = d;
    }
}

// flush block's u contribution, chunked layout: UP[t>>3][bid][t&7] (uncached)
__device__ __forceinline__ void flush_up(float* UP, const float* ubuf,
                                         int bid, int tid) {
    #pragma unroll
    for (int r = 0; r < 4; ++r) {
        const int t = tid + 512*r;
        astore(&UP[(size_t)(t >> 3)*2048 + bid*8 + (tid & 7)], ubuf[t]);
    }
}

// Deterministic reduce at this block's owned chunk (t=8*bid..+8): one
// contiguous 8KB CACHED read (UP slot is written-once this launch).
__device__ __forceinline__ void reduce_up(const float* __restrict__ UP,
                                          float* udst, float (*red2)[8],
                                          float* ufin, float* uhrow,
                                          int bid, int tid) {
    const int off = tid & 7, g = tid >> 3;
    const float* base = UP + (size_t)bid*2048;
    float s = 0.f;
    #pragma unroll
    for (int i = 0; i < 4; ++i) s += base[(4*g + i)*8 + off];
    red2[g][off] = s;
    __syncthreads();
    if (tid < 8) {
        float u = 0.f;
        #pragma unroll
        for (int g2 = 0; g2 < 64; ++g2) u += red2[g2][tid];   // fixed order
        ufin[tid] = u;
        uhrow[tid] = u;
        astore(&udst[8*bid + tid], u);
    }
    __syncthreads();
}

// y slab partial: acc = -sum_t u[t]*R[t, my col4] over this thread's 32 rows
__device__ __forceinline__ float4 y_pass(const float4 (&rr)[RPT],
                                         const float* u, int rg) {
    float4 acc = make_float4(0.f, 0.f, 0.f, 0.f);
    #pragma unroll
    for (int i = 0; i < RPT; ++i) {
        const float ut = u[rg + 64*i];
        acc.x -= ut*rr[i].x; acc.y -= ut*rr[i].y;
        acc.z -= ut*rr[i].z; acc.w -= ut*rr[i].w;
    }
    return acc;
}

// Reduce per-thread y partials (over rg) into ysl[32]. Fixed order everywhere.
__device__ __forceinline__ void y_reduce(float4 acc, float (*red)[8][4],
                                         float* ysl, int wave, int lane, int tid) {
    #pragma unroll
    for (int m = 8; m < 64; m <<= 1) {
        acc.x += __shfl_xor(acc.x, m, 64); acc.y += __shfl_xor(acc.y, m, 64);
        acc.z += __shfl_xor(acc.z, m, 64); acc.w += __shfl_xor(acc.w, m, 64);
    }
    if (lane < 8) {
        red[wave][lane][0] = acc.x; red[wave][lane][1] = acc.y;
        red[wave][lane][2] = acc.z; red[wave][lane][3] = acc.w;
    }
    __syncthreads();
    if (tid < 32) {
        const int g = tid >> 2, comp = tid & 3;
        float s = 0.f;
        #pragma unroll
        for (int w = 0; w < 8; ++w) s += red[w][g][comp];
        ysl[g*4 + comp] = s;
    }
    __syncthreads();
}

__global__ __launch_bounds__(NTHR, 2) void k_all(
    const float* __restrict__ Rm, const float* __restrict__ f,
    const float* __restrict__ Dm, float* __restrict__ out,
    float* __restrict__ ws)
{
    __shared__ __align__(16) float ubuf[2048];
    __shared__ float red2[64][8];
    __shared__ float red[8][8][4];
    __shared__ float ufin[8];
    __shared__ float uh[17][8];
    __shared__ __align__(16) float ysl[32];
    __shared__ __align__(16) float dirs[32];
    __shared__ __align__(16) float fsl[32];
    __shared__ float Wh[LORD][32];
    __shared__ float bh[LORD];
    __shared__ float alph[LORD];
    __shared__ float dotl[LORD];
    __shared__ float cf[LORD];
    __shared__ float misc[4];   // [0]=b2j  [2]=ff  [3]=uu

    float* coefg   = ws + G_COEF;
    unsigned* barc = (unsigned*)(ws + G_BARC);
    unsigned* relw = (unsigned*)(ws + G_RELW);
    float* uraw = ws + G_URAW;
    float* UUP  = ws + G_UUP;
    float* FFP  = ws + G_FFP;
    float* B2P  = ws + G_B2P;
    float* DP   = ws + G_DP;
    float* NUMP = ws + G_NUMP;
    float* DENP = ws + G_DENP;
    float* UPB  = ws + G_UPB;
    int bar = 0;

    const int tid = threadIdx.x, bid = blockIdx.x;
    const int cg = tid & 7, rg = tid >> 3;
    const int lane = tid & 63, wave = tid >> 6;

    // Load R column-slab into registers ONCE.
    const float4* R4 = (const float4*)Rm;
    float4 rr[RPT];
    #pragma unroll
    for (int i = 0; i < RPT; ++i)
        rr[i] = R4[(size_t)(rg + 64*i)*NC4 + (bid << 3) + cg];

    // ===== I1: f slab -> LDS ; FFP partial ; u_init partials (UP slot 16) =====
    if (wave == 0) {
        float4 fv = make_float4(0.f, 0.f, 0.f, 0.f);
        if (lane < 8) { fv = ((const float4*)f)[(bid << 3) + lane];
                        ((float4*)fsl)[lane] = fv; }
        float s2 = fv.x*fv.x + fv.y*fv.y + fv.z*fv.z + fv.w*fv.w;
        s2 += __shfl_xor(s2, 1, 64);
        s2 += __shfl_xor(s2, 2, 64);
        s2 += __shfl_xor(s2, 4, 64);
        if (lane == 0) astore(&FFP[bid], s2);
    }
    __syncthreads();
    u_pass_lds(rr, fsl, ubuf, rg, cg);
    __syncthreads();
    flush_up(UPB + (size_t)16*NBLK*2048, ubuf, bid, tid);
    gbar(barc, relw, bar++, bid);

    // ===== I2: reduce UP16 -> uraw[16]=Rf ; uu partial ; ff reduce (all) =====
    reduce_up(UPB + (size_t)16*NBLK*2048, uraw + 16*2048, red2, ufin, uh[16],
              bid, tid);
    if (tid == 0) {
        float pd = 0.f;
        #pragma unroll
        for (int t = 0; t < 8; ++t) pd += ufin[t]*ufin[t];
        astore(&UUP[bid], pd);
    }
    if (wave == 1) {   // every block reduces FFP identically (fixed order)
        float s = 0.f;
        #pragma unroll
        for (int i = 0; i < 4; ++i) s += FFP[lane + 64*i];
        s = wave_sum64(s);
        if (lane == 0) misc[2] = s;
    }
    gbar(barc, relw, bar++, bid);

    // ===== I3: uu reduce (all) ; y=Hf ; W0 ; b2 partial ; u(W0) slot 0 =====
    if (wave == 0) {
        float s = 0.f;
        #pragma unroll
        for (int i = 0; i < 4; ++i) s += UUP[lane + 64*i];
        s = wave_sum64(s);
        if (lane == 0) misc[3] = s;
    }
    #pragma unroll
    for (int r = 0; r < 4; ++r)
        ubuf[tid + 512*r] = uraw[16*2048 + tid + 512*r];
    __syncthreads();
    {
        float4 acc = y_pass(rr, ubuf, rg);
        y_reduce(acc, red, ysl, wave, lane, tid);
        const float E = -misc[3] / (misc[2] + 1e-15f);
        float v = 0.f;
        if (tid < 32) { v = E*fsl[tid] - ysl[tid]; Wh[0][tid] = v; }
        if (wave == 0) {
            float s = (lane < 32) ? v*v : 0.f;
            s = wave_sum64(s);
            if (lane == 0) astore(&B2P[0*256 + bid], s);
        }
        __syncthreads();
        u_pass_lds(rr, Wh[0], ubuf, rg, cg);
        __syncthreads();
        flush_up(UPB + (size_t)0*NBLK*2048, ubuf, bid, tid);
    }
    gbar(barc, relw, bar++, bid);

    // ===== Lanczos steps j=0..15 =====
    for (int j = 0; j < LORD; ++j) {
        float* UPj = UPB + (size_t)j*NBLK*2048;
        float* DPj = DP + (size_t)j*17*256;
        // --- Phase 1: reduce u ; dot partials vs history ; b2 reduce (all) ---
        reduce_up(UPj, uraw + (size_t)j*2048, red2, ufin, uh[j], bid, tid);
        if (wave == 0 && lane <= j) {
            float pd = 0.f;
            #pragma unroll 1
            for (int t = 0; t < 8; ++t) pd += ufin[t] * uh[lane][t];
            astore(&DPj[lane*256 + bid], pd);
        }
        if (wave == 1) {   // every block reduces B2P[j] identically
            float s = 0.f;
            #pragma unroll
            for (int i = 0; i < 4; ++i) s += B2P[j*256 + lane + 64*i];
            s = wave_sum64(s);
            if (lane == 0) misc[0] = s;
        }
        gbar(barc, relw, bar++, bid);

        // --- Phase 2: u broadcast (early issue); dots reduce; y; W_{j+1} ---
        float tmp[4];
        if (j < LORD - 1) {
            #pragma unroll
            for (int r = 0; r < 4; ++r)
                tmp[r] = uraw[(size_t)j*2048 + tid + 512*r];
        }
        for (int k = wave; k <= j; k += 8) {
            float s = 0.f;
            #pragma unroll
            for (int i = 0; i < 4; ++i) s += DPj[k*256 + lane + 64*i];
            s = wave_sum64(s);
            if (lane == 0) dotl[k] = s;
        }
        __syncthreads();
        const float b2j = misc[0];
        const float bj  = sqrtf(fmaxf(b2j, 1e-60f));   // ref: w/max(b,1e-30)
        if (tid == 0) {
            bh[j]   = bj;
            alph[j] = -dotl[j] / fmaxf(b2j, 1e-60f);
        }
        if (j < LORD - 1) {
            const float inv = 1.0f / bj;
            #pragma unroll
            for (int r = 0; r < 4; ++r) ubuf[tid + 512*r] = tmp[r] * inv;
            __syncthreads();
            float4 acc = y_pass(rr, ubuf, rg);
            y_reduce(acc, red, ysl, wave, lane, tid);
            // W_{j+1} = y + sum_{k<=j} dot_jk/(b_j b_k^2) W_k  (full reorth)
            float v = 0.f;
            if (tid < 32) {
                v = ysl[tid];
                for (int k = 0; k <= j; ++k)
                    v += (dotl[k] / (bj * bh[k] * bh[k])) * Wh[k][tid];
                Wh[j+1][tid] = v;
            }
            if (wave == 0) {
                float s = (lane < 32) ? v*v : 0.f;
                s = wave_sum64(s);
                if (lane == 0) astore(&B2P[(j+1)*256 + bid], s);
            }
            __syncthreads();
            u_pass_lds(rr, Wh[j+1], ubuf, rg, cg);
            __syncthreads();
            flush_up(UPB + (size_t)(j+1)*NBLK*2048, ubuf, bid, tid);
        } else {
            __syncthreads();   // alph[15]/bh[15] visible
            // coeffs = normF * exp(-tau*T) e0 via fp64 Taylor (block 0)
            if (bid == 0 && wave == 0) {
                double a = 0.0, bl = 0.0;
                if (lane < LORD)     a  = (double)alph[lane];
                if (lane < LORD - 1) bl = (double)bh[lane + 1];
                double bprev = __shfl_up(bl, 1, 64);
                if (lane == 0) bprev = 0.0;
                if (lane >= LORD) { a = 0.0; bl = 0.0; bprev = 0.0; }
                double v = (lane == 0) ? 1.0 : 0.0;
                double accd = v;
                for (int n = 1; n <= 30; ++n) {
                    double vm = __shfl_up(v, 1, 64);
                    if (lane == 0) vm = 0.0;
                    double vp = __shfl_down(v, 1, 64);
                    if (lane >= LORD - 1) vp = 0.0;
                    const double tv = a*v + bprev*vm + bl*vp;
                    v = tv * (-0.08 / (double)n);
                    accd += v;
                }
                if (lane < LORD)
                    astore(&coefg[lane], (float)accd * bh[0]);
            }
        }
        gbar(barc, relw, bar++, bid);
    }

    // ===== F1: dir slab from LDS W history ; num/den partials =====
    if (wave == 0 && lane < 16) cf[lane] = coefg[lane];
    __syncthreads();
    if (tid < 32) {
        float s = 0.f;
        #pragma unroll
        for (int l = 0; l < LORD; ++l) s += cf[l] * Wh[l][tid] / bh[l];
        dirs[tid] = s;
    }
    __syncthreads();
    if (wave == 0 && lane < 16) {
        const float4* Dp = (const float4*)Dm + (size_t)lane*NC4 + (bid << 3);
        float num = 0.f, den = 0.f;
        #pragma unroll
        for (int g = 0; g < 8; ++g) {
            const float4 dv = Dp[g];
            const float4 dr = ((const float4*)dirs)[g];
            num += dv.x*dr.x + dv.y*dr.y + dv.z*dr.z + dv.w*dr.w;
            den += dv.x*dv.x + dv.y*dv.y + dv.z*dv.z + dv.w*dv.w;
        }
        astore(&NUMP[lane*256 + bid], num);
        astore(&DENP[lane*256 + bid], den);
    }
    gbar(barc, relw, bar++, bid);

    // ===== F2: block 0 reduces num/den deterministically, writes out =====
    if (bid == 0) {
        for (int p = wave; p < 16; p += 8) {
            float n = 0.f, d = 0.f;
            #pragma unroll
            for (int i = 0; i < 4; ++i) {
                n += NUMP[p*256 + lane + 64*i];
                d += DENP[p*256 + lane + 64*i];
            }
            n = wave_sum64(n);
            d = wave_sum64(d);
            if (lane == 0) out[p] = n / (d + 1e-4f);
        }
    }
}

extern "C" void kernel_launch(void* const* d_in, const int* in_sizes, int n_in,
                              void* d_out, int out_size, void* d_ws, size_t ws_size,
                              hipStream_t stream)
{
    (void)in_sizes; (void)n_in; (void)out_size; (void)ws_size;
    const float* f  = (const float*)d_in[0];
    const float* Rm = (const float*)d_in[1];
    const float* Dm = (const float*)d_in[2];
    float* outp = (float*)d_out;
    float* ws   = (float*)d_ws;
    // Zero coef + padded barrier counters/release words (~320 KB). All rotated
    // payload buffers are written before their single read each launch.
    hipMemsetAsync(ws, 0, G_ZEND * sizeof(float), stream);
    void* args[] = { (void*)&Rm, (void*)&f, (void*)&Dm, (void*)&outp, (void*)&ws };
    hipLaunchCooperativeKernel((const void*)k_all, dim3(NBLK), dim3(NTHR),
                               args, 0, stream);
}